// Round 1
// baseline (661.658 us; speedup 1.0000x reference)
//
#include <hip/hip_runtime.h>

constexpr int H = 64;
constexpr int PAD = 68;   // LDS row stride in floats (16B-aligned, breaks bank conflicts)

// h[n][j] = x[n] * ne_w[j] + ne_b[j], float4 per thread
__global__ __launch_bounds__(256) void encode_kernel(
    const float* __restrict__ x, const float* __restrict__ nw,
    const float* __restrict__ nb, float* __restrict__ hout, int N)
{
    int idx = blockIdx.x * 256 + threadIdx.x;        // over N*16 float4s
    if (idx >= N * 16) return;
    int n = idx >> 4, c = idx & 15;
    float xv = x[n];
    float4 w = ((const float4*)nw)[c];
    float4 b = ((const float4*)nb)[c];
    float4 r;
    r.x = fmaf(xv, w.x, b.x);
    r.y = fmaf(xv, w.y, b.y);
    r.z = fmaf(xv, w.z, b.z);
    r.w = fmaf(xv, w.w, b.w);
    ((float4*)hout)[idx] = r;
}

// per-edge: m = relu(h[src] + ea*ee_w + ee_b); atomicAdd to agg[dst]
// wave per edge (lane = channel), 4 edges per wave, 16 edges per block
__global__ __launch_bounds__(256) void scatter_kernel(
    const float* __restrict__ h, const int* __restrict__ ei,
    const float* __restrict__ eattr,
    const float* __restrict__ ew, const float* __restrict__ eb,
    float* __restrict__ agg, int E)
{
    int lane = threadIdx.x & 63;
    int wid  = threadIdx.x >> 6;          // 0..3
    float wj = ew[lane], bj = eb[lane];
    int kbase = blockIdx.x * 16 + wid * 4;
#pragma unroll
    for (int m = 0; m < 4; ++m) {
        int k = kbase + m;
        if (k >= E) break;
        int src = ei[k];
        int dst = ei[E + k];
        float ea = eattr[k];
        float msg = fmaf(ea, wj, bj) + h[src * H + lane];
        msg = fmaxf(msg, 0.f);
        atomicAdd(agg + dst * H + lane, msg);
    }
}

// per 64-node tile: z = h + agg; u = relu(z@w1+b1); out = relu(u@w2+b2)
// 256 threads, each computes a 4x4 (node x outch) tile. LDS-tiled fp32 GEMM.
__global__ __launch_bounds__(256) void mlp_kernel(
    const float* __restrict__ h, const float* __restrict__ agg,
    const float* __restrict__ w1, const float* __restrict__ b1,
    const float* __restrict__ w2, const float* __restrict__ b2,
    float* __restrict__ out, int N)
{
    __shared__ float zT[H * PAD];   // [i][n]  (input-dim major, node minor)
    __shared__ float wS[H * PAD];   // [i][j]
    int tid = threadIdx.x;
    int nb = blockIdx.x * 64;

    // ---- stage w1: thread covers 16 consecutive floats of row i ----
    {
        int i  = tid >> 2;
        int jc = (tid & 3) * 16;
        const float4* s = (const float4*)(w1 + i * H + jc);
        float4* d = (float4*)(wS + i * PAD + jc);
        d[0] = s[0]; d[1] = s[1]; d[2] = s[2]; d[3] = s[3];
    }
    // ---- stage zT = (h+agg) transposed ----
    {
        int nl = tid >> 2;
        int n  = nb + nl;
        int ic = (tid & 3) * 16;
        if (n < N) {
#pragma unroll
            for (int m = 0; m < 4; ++m) {
                float4 hv = *(const float4*)(h   + (size_t)n * H + ic + m * 4);
                float4 av = *(const float4*)(agg + (size_t)n * H + ic + m * 4);
                zT[(ic + m * 4 + 0) * PAD + nl] = hv.x + av.x;
                zT[(ic + m * 4 + 1) * PAD + nl] = hv.y + av.y;
                zT[(ic + m * 4 + 2) * PAD + nl] = hv.z + av.z;
                zT[(ic + m * 4 + 3) * PAD + nl] = hv.w + av.w;
            }
        } else {
#pragma unroll
            for (int m = 0; m < 4; ++m)
#pragma unroll
                for (int q = 0; q < 4; ++q)
                    zT[(ic + m * 4 + q) * PAD + nl] = 0.f;
        }
    }
    __syncthreads();

    int tj = tid & 15, tn = tid >> 4;
    int j0 = tj * 4, n0 = tn * 4;

    // ---- matmul 1: acc[p][q] = sum_i zT[i][n0+p] * w1[i][j0+q] ----
    float acc[4][4] = {};
#pragma unroll 4
    for (int i = 0; i < H; ++i) {
        float4 a = *(const float4*)(zT + i * PAD + n0);
        float4 b = *(const float4*)(wS + i * PAD + j0);
        float av[4] = {a.x, a.y, a.z, a.w};
        float bv[4] = {b.x, b.y, b.z, b.w};
#pragma unroll
        for (int p = 0; p < 4; ++p)
#pragma unroll
            for (int q = 0; q < 4; ++q)
                acc[p][q] = fmaf(av[p], bv[q], acc[p][q]);
    }
    float4 bb1 = *(const float4*)(b1 + j0);
    float u[4][4];
#pragma unroll
    for (int p = 0; p < 4; ++p) {
        u[p][0] = fmaxf(acc[p][0] + bb1.x, 0.f);
        u[p][1] = fmaxf(acc[p][1] + bb1.y, 0.f);
        u[p][2] = fmaxf(acc[p][2] + bb1.z, 0.f);
        u[p][3] = fmaxf(acc[p][3] + bb1.w, 0.f);
    }
    __syncthreads();   // all reads of zT/wS done

    // ---- write uT into zT buffer; reload wS with w2 ----
#pragma unroll
    for (int p = 0; p < 4; ++p)
#pragma unroll
        for (int q = 0; q < 4; ++q)
            zT[(j0 + q) * PAD + (n0 + p)] = u[p][q];
    {
        int i  = tid >> 2;
        int jc = (tid & 3) * 16;
        const float4* s = (const float4*)(w2 + i * H + jc);
        float4* d = (float4*)(wS + i * PAD + jc);
        d[0] = s[0]; d[1] = s[1]; d[2] = s[2]; d[3] = s[3];
    }
    __syncthreads();

    // ---- matmul 2 ----
    float acc2[4][4] = {};
#pragma unroll 4
    for (int i = 0; i < H; ++i) {
        float4 a = *(const float4*)(zT + i * PAD + n0);
        float4 b = *(const float4*)(wS + i * PAD + j0);
        float av[4] = {a.x, a.y, a.z, a.w};
        float bv[4] = {b.x, b.y, b.z, b.w};
#pragma unroll
        for (int p = 0; p < 4; ++p)
#pragma unroll
            for (int q = 0; q < 4; ++q)
                acc2[p][q] = fmaf(av[p], bv[q], acc2[p][q]);
    }
    float4 bb2 = *(const float4*)(b2 + j0);
#pragma unroll
    for (int p = 0; p < 4; ++p) {
        int n = nb + n0 + p;
        if (n < N) {
            float4 r;
            r.x = fmaxf(acc2[p][0] + bb2.x, 0.f);
            r.y = fmaxf(acc2[p][1] + bb2.y, 0.f);
            r.z = fmaxf(acc2[p][2] + bb2.z, 0.f);
            r.w = fmaxf(acc2[p][3] + bb2.w, 0.f);
            *(float4*)(out + (size_t)n * H + j0) = r;
        }
    }
}

// mean-pool stage 1: running per-graph accumulation over a contiguous chunk
// (batch is sorted) with one atomic flush per segment boundary per block.
__global__ __launch_bounds__(64) void pool_kernel(
    const float* __restrict__ h, const int* __restrict__ batch,
    float* __restrict__ sums, float* __restrict__ counts, int N)
{
    int lane = threadIdx.x;
    int start = blockIdx.x * 256;
    if (start >= N) return;
    int end = start + 256; if (end > N) end = N;
    int cur = batch[start];
    float acc = 0.f;
    int cnt = 0;
    for (int n = start; n < end; ++n) {
        int g = batch[n];
        if (g != cur) {
            atomicAdd(sums + cur * H + lane, acc);
            if (lane == 0) atomicAdd(counts + cur, (float)cnt);
            acc = 0.f; cnt = 0; cur = g;
        }
        acc += h[(size_t)n * H + lane];
        cnt++;
    }
    atomicAdd(sums + cur * H + lane, acc);
    if (lane == 0) atomicAdd(counts + cur, (float)cnt);
}

__global__ void div_kernel(const float* __restrict__ sums,
                           const float* __restrict__ counts,
                           float* __restrict__ out)
{
    int g = blockIdx.x, j = threadIdx.x;
    out[g * H + j] = sums[g * H + j] / fmaxf(counts[g], 1.0f);
}

extern "C" void kernel_launch(void* const* d_in, const int* in_sizes, int n_in,
                              void* d_out, int out_size, void* d_ws, size_t ws_size,
                              hipStream_t stream)
{
    const float* x     = (const float*)d_in[0];
    const int*   ei    = (const int*)d_in[1];
    const float* eattr = (const float*)d_in[2];
    const int*   batch = (const int*)d_in[3];
    const float* ne_w  = (const float*)d_in[4];
    const float* ne_b  = (const float*)d_in[5];
    const float* ee_w  = (const float*)d_in[6];
    const float* ee_b  = (const float*)d_in[7];
    const float* c1w1  = (const float*)d_in[8];
    const float* c1b1  = (const float*)d_in[9];
    const float* c1w2  = (const float*)d_in[10];
    const float* c1b2  = (const float*)d_in[11];
    const float* c2w1  = (const float*)d_in[12];
    const float* c2b1  = (const float*)d_in[13];
    const float* c2w2  = (const float*)d_in[14];
    const float* c2b2  = (const float*)d_in[15];

    const int N = in_sizes[0];        // 100000
    const int E = in_sizes[2];        // 1200000 (edge_attr is [E,1])

    float* h      = (float*)d_ws;
    float* agg    = h + (size_t)N * H;
    float* sums   = agg + (size_t)N * H;
    float* counts = sums + 64 * H;

    // encode nodes
    encode_kernel<<<(N * 16 + 255) / 256, 256, 0, stream>>>(x, ne_w, ne_b, h, N);

    const int scatterGrid = (E + 15) / 16;
    const int mlpGrid = (N + 63) / 64;

    // ---- layer 1 ----
    hipMemsetAsync(agg, 0, (size_t)N * H * sizeof(float), stream);
    scatter_kernel<<<scatterGrid, 256, 0, stream>>>(h, ei, eattr, ee_w, ee_b, agg, E);
    mlp_kernel<<<mlpGrid, 256, 0, stream>>>(h, agg, c1w1, c1b1, c1w2, c1b2, h, N);

    // ---- layer 2 ----
    hipMemsetAsync(agg, 0, (size_t)N * H * sizeof(float), stream);
    scatter_kernel<<<scatterGrid, 256, 0, stream>>>(h, ei, eattr, ee_w, ee_b, agg, E);
    mlp_kernel<<<mlpGrid, 256, 0, stream>>>(h, agg, c2w1, c2b1, c2w2, c2b2, h, N);

    // ---- mean pool ----
    hipMemsetAsync(sums, 0, (64 * H + 64) * sizeof(float), stream);
    pool_kernel<<<(N + 255) / 256, 64, 0, stream>>>(h, batch, sums, counts, N);
    div_kernel<<<64, 64, 0, stream>>>(sums, counts, (float*)d_out);
}

// Round 2
// 451.237 us; speedup vs baseline: 1.4663x; 1.4663x over previous
//
#include <hip/hip_runtime.h>

constexpr int H = 64;
constexpr int PAD = 68;   // LDS row stride in floats (16B-aligned, breaks bank conflicts)

// ---------------- encode: h[n][j] = x[n] * ne_w[j] + ne_b[j] ----------------
__global__ __launch_bounds__(256) void encode_kernel(
    const float* __restrict__ x, const float* __restrict__ nw,
    const float* __restrict__ nb, float* __restrict__ hout, int N)
{
    int idx = blockIdx.x * 256 + threadIdx.x;        // over N*16 float4s
    if (idx >= N * 16) return;
    int n = idx >> 4, c = idx & 15;
    float xv = x[n];
    float4 w = ((const float4*)nw)[c];
    float4 b = ((const float4*)nb)[c];
    float4 r;
    r.x = fmaf(xv, w.x, b.x);
    r.y = fmaf(xv, w.y, b.y);
    r.z = fmaf(xv, w.z, b.z);
    r.w = fmaf(xv, w.w, b.w);
    ((float4*)hout)[idx] = r;
}

// ---------------- CSR build ----------------
__global__ __launch_bounds__(256) void hist_kernel(
    const int* __restrict__ ei, int* __restrict__ deg, int E)
{
    int k = blockIdx.x * 256 + threadIdx.x;
    if (k < E) atomicAdd(deg + ei[E + k], 1);
}

// block-local exclusive scan (chunk=256) + block sums
__global__ __launch_bounds__(256) void scan1_kernel(
    const int* __restrict__ deg, int* __restrict__ off,
    int* __restrict__ bsum, int N)
{
    __shared__ int s[256];
    int t = threadIdx.x, i = blockIdx.x * 256 + t;
    int v = (i < N) ? deg[i] : 0;
    s[t] = v;
    __syncthreads();
#pragma unroll
    for (int d = 1; d < 256; d <<= 1) {
        int x = (t >= d) ? s[t - d] : 0;
        __syncthreads();
        s[t] += x;
        __syncthreads();
    }
    if (i < N) off[i] = s[t] - v;           // exclusive
    if (t == 255) bsum[blockIdx.x] = s[255];
}

// single-block exclusive scan of block sums (nb <= 512)
__global__ __launch_bounds__(512) void scan2_kernel(int* __restrict__ bsum, int nb)
{
    __shared__ int s[512];
    int t = threadIdx.x;
    int v = (t < nb) ? bsum[t] : 0;
    s[t] = v;
    __syncthreads();
#pragma unroll
    for (int d = 1; d < 512; d <<= 1) {
        int x = (t >= d) ? s[t - d] : 0;
        __syncthreads();
        s[t] += x;
        __syncthreads();
    }
    if (t < nb) bsum[t] = s[t] - v;         // exclusive
}

__global__ __launch_bounds__(256) void scan3_kernel(
    int* __restrict__ off, const int* __restrict__ bsum, int N)
{
    int i = blockIdx.x * 256 + threadIdx.x;
    if (i < N) off[i] += bsum[blockIdx.x];
}

// fill CSR: cursor starts as a copy of off; after this kernel cursor[n] == end(n)
__global__ __launch_bounds__(256) void fill_kernel(
    const int* __restrict__ ei, const float* __restrict__ eattr,
    int* __restrict__ cursor, int2* __restrict__ csr, int E)
{
    int k = blockIdx.x * 256 + threadIdx.x;
    if (k >= E) return;
    int src = ei[k];
    int dst = ei[E + k];
    float ea = eattr[k];
    int pos = atomicAdd(cursor + dst, 1);
    csr[pos] = make_int2(src, __float_as_int(ea));
}

// ---------------- gather: z[n] = h[n] + sum_{e->n} relu(h[src] + ea*ew + eb) ----
// one wave per node, lane = channel
__global__ __launch_bounds__(256) void gather_kernel(
    const float* __restrict__ h, const int2* __restrict__ csr,
    const int* __restrict__ off, const int* __restrict__ endp,
    const float* __restrict__ ew, const float* __restrict__ eb,
    float* __restrict__ z, int N)
{
    int lane = threadIdx.x & 63;
    int wid  = threadIdx.x >> 6;
    int n = blockIdx.x * 4 + wid;
    if (n >= N) return;
    float wj = ew[lane], bj = eb[lane];
    int e  = off[n];
    int e1 = endp[n];
    float acc = h[(size_t)n * H + lane];    // self term (eps = 0)
    for (; e + 1 < e1; e += 2) {
        int2 r0 = csr[e];
        int2 r1 = csr[e + 1];
        float m0 = fmaf(__int_as_float(r0.y), wj, bj) + h[(size_t)r0.x * H + lane];
        float m1 = fmaf(__int_as_float(r1.y), wj, bj) + h[(size_t)r1.x * H + lane];
        acc += fmaxf(m0, 0.f) + fmaxf(m1, 0.f);
    }
    if (e < e1) {
        int2 r = csr[e];
        acc += fmaxf(fmaf(__int_as_float(r.y), wj, bj) + h[(size_t)r.x * H + lane], 0.f);
    }
    z[(size_t)n * H + lane] = acc;
}

// ---------------- per 64-node tile MLP: u = relu(z@w1+b1); out = relu(u@w2+b2) ----
__global__ __launch_bounds__(256) void mlp_kernel(
    const float* __restrict__ z, const float* __restrict__ w1,
    const float* __restrict__ b1, const float* __restrict__ w2,
    const float* __restrict__ b2, float* __restrict__ out, int N)
{
    __shared__ float zT[H * PAD];   // [i][n]  (input-dim major, node minor)
    __shared__ float wS[H * PAD];   // [i][j]
    int tid = threadIdx.x;
    int nb = blockIdx.x * 64;

    // ---- stage w1 ----
    {
        int i  = tid >> 2;
        int jc = (tid & 3) * 16;
        const float4* s = (const float4*)(w1 + i * H + jc);
        float4* d = (float4*)(wS + i * PAD + jc);
        d[0] = s[0]; d[1] = s[1]; d[2] = s[2]; d[3] = s[3];
    }
    // ---- stage zT (transposed) ----
    {
        int nl = tid >> 2;
        int n  = nb + nl;
        int ic = (tid & 3) * 16;
        if (n < N) {
#pragma unroll
            for (int m = 0; m < 4; ++m) {
                float4 zv = *(const float4*)(z + (size_t)n * H + ic + m * 4);
                zT[(ic + m * 4 + 0) * PAD + nl] = zv.x;
                zT[(ic + m * 4 + 1) * PAD + nl] = zv.y;
                zT[(ic + m * 4 + 2) * PAD + nl] = zv.z;
                zT[(ic + m * 4 + 3) * PAD + nl] = zv.w;
            }
        } else {
#pragma unroll
            for (int m = 0; m < 4; ++m)
#pragma unroll
                for (int q = 0; q < 4; ++q)
                    zT[(ic + m * 4 + q) * PAD + nl] = 0.f;
        }
    }
    __syncthreads();

    int tj = tid & 15, tn = tid >> 4;
    int j0 = tj * 4, n0 = tn * 4;

    // ---- matmul 1 ----
    float acc[4][4] = {};
#pragma unroll 4
    for (int i = 0; i < H; ++i) {
        float4 a = *(const float4*)(zT + i * PAD + n0);
        float4 b = *(const float4*)(wS + i * PAD + j0);
        float av[4] = {a.x, a.y, a.z, a.w};
        float bv[4] = {b.x, b.y, b.z, b.w};
#pragma unroll
        for (int p = 0; p < 4; ++p)
#pragma unroll
            for (int q = 0; q < 4; ++q)
                acc[p][q] = fmaf(av[p], bv[q], acc[p][q]);
    }
    float4 bb1 = *(const float4*)(b1 + j0);
    float u[4][4];
#pragma unroll
    for (int p = 0; p < 4; ++p) {
        u[p][0] = fmaxf(acc[p][0] + bb1.x, 0.f);
        u[p][1] = fmaxf(acc[p][1] + bb1.y, 0.f);
        u[p][2] = fmaxf(acc[p][2] + bb1.z, 0.f);
        u[p][3] = fmaxf(acc[p][3] + bb1.w, 0.f);
    }
    __syncthreads();

    // ---- write uT into zT; reload wS with w2 ----
#pragma unroll
    for (int p = 0; p < 4; ++p)
#pragma unroll
        for (int q = 0; q < 4; ++q)
            zT[(j0 + q) * PAD + (n0 + p)] = u[p][q];
    {
        int i  = tid >> 2;
        int jc = (tid & 3) * 16;
        const float4* s = (const float4*)(w2 + i * H + jc);
        float4* d = (float4*)(wS + i * PAD + jc);
        d[0] = s[0]; d[1] = s[1]; d[2] = s[2]; d[3] = s[3];
    }
    __syncthreads();

    // ---- matmul 2 ----
    float acc2[4][4] = {};
#pragma unroll 4
    for (int i = 0; i < H; ++i) {
        float4 a = *(const float4*)(zT + i * PAD + n0);
        float4 b = *(const float4*)(wS + i * PAD + j0);
        float av[4] = {a.x, a.y, a.z, a.w};
        float bv[4] = {b.x, b.y, b.z, b.w};
#pragma unroll
        for (int p = 0; p < 4; ++p)
#pragma unroll
            for (int q = 0; q < 4; ++q)
                acc2[p][q] = fmaf(av[p], bv[q], acc2[p][q]);
    }
    float4 bb2 = *(const float4*)(b2 + j0);
#pragma unroll
    for (int p = 0; p < 4; ++p) {
        int n = nb + n0 + p;
        if (n < N) {
            float4 r;
            r.x = fmaxf(acc2[p][0] + bb2.x, 0.f);
            r.y = fmaxf(acc2[p][1] + bb2.y, 0.f);
            r.z = fmaxf(acc2[p][2] + bb2.z, 0.f);
            r.w = fmaxf(acc2[p][3] + bb2.w, 0.f);
            *(float4*)(out + (size_t)n * H + j0) = r;
        }
    }
}

// ---------------- mean pool (batch sorted): chunked running accumulation ----
__global__ __launch_bounds__(64) void pool_kernel(
    const float* __restrict__ h, const int* __restrict__ batch,
    float* __restrict__ sums, float* __restrict__ counts, int N)
{
    int lane = threadIdx.x;
    int start = blockIdx.x * 256;
    if (start >= N) return;
    int end = start + 256; if (end > N) end = N;
    int cur = batch[start];
    float acc = 0.f;
    int cnt = 0;
    for (int n = start; n < end; ++n) {
        int g = batch[n];
        if (g != cur) {
            atomicAdd(sums + cur * H + lane, acc);
            if (lane == 0) atomicAdd(counts + cur, (float)cnt);
            acc = 0.f; cnt = 0; cur = g;
        }
        acc += h[(size_t)n * H + lane];
        cnt++;
    }
    atomicAdd(sums + cur * H + lane, acc);
    if (lane == 0) atomicAdd(counts + cur, (float)cnt);
}

__global__ void div_kernel(const float* __restrict__ sums,
                           const float* __restrict__ counts,
                           float* __restrict__ out)
{
    int g = blockIdx.x, j = threadIdx.x;
    out[g * H + j] = sums[g * H + j] / fmaxf(counts[g], 1.0f);
}

extern "C" void kernel_launch(void* const* d_in, const int* in_sizes, int n_in,
                              void* d_out, int out_size, void* d_ws, size_t ws_size,
                              hipStream_t stream)
{
    const float* x     = (const float*)d_in[0];
    const int*   ei    = (const int*)d_in[1];
    const float* eattr = (const float*)d_in[2];
    const int*   batch = (const int*)d_in[3];
    const float* ne_w  = (const float*)d_in[4];
    const float* ne_b  = (const float*)d_in[5];
    const float* ee_w  = (const float*)d_in[6];
    const float* ee_b  = (const float*)d_in[7];
    const float* c1w1  = (const float*)d_in[8];
    const float* c1b1  = (const float*)d_in[9];
    const float* c1w2  = (const float*)d_in[10];
    const float* c1b2  = (const float*)d_in[11];
    const float* c2w1  = (const float*)d_in[12];
    const float* c2b1  = (const float*)d_in[13];
    const float* c2w2  = (const float*)d_in[14];
    const float* c2b2  = (const float*)d_in[15];

    const int N = in_sizes[0];        // 100000
    const int E = in_sizes[2];        // 1200000 (edge_attr is [E,1])

    // ---- workspace carve-up (all offsets 8B-aligned) ----
    float* h      = (float*)d_ws;                    // N*H floats
    float* z      = h + (size_t)N * H;               // N*H floats
    float* sums   = z + (size_t)N * H;               // 64*H
    float* counts = sums + 64 * H;                   // 64
    int*   deg    = (int*)(counts + 64);             // N
    int*   off    = deg + N;                         // N
    int*   cursor = off + N;                         // N  (ends after fill)
    int*   bsum   = cursor + N;                      // 512
    int2*  csr    = (int2*)(bsum + 512);             // E int2 (offset even)

    const int nScanBlocks = (N + 255) / 256;
    const int eGrid = (E + 255) / 256;

    // encode nodes (independent of CSR build)
    encode_kernel<<<(N * 16 + 255) / 256, 256, 0, stream>>>(x, ne_w, ne_b, h, N);

    // ---- CSR build (once, reused by both layers) ----
    hipMemsetAsync(deg, 0, (size_t)N * sizeof(int), stream);
    hist_kernel<<<eGrid, 256, 0, stream>>>(ei, deg, E);
    scan1_kernel<<<nScanBlocks, 256, 0, stream>>>(deg, off, bsum, N);
    scan2_kernel<<<1, 512, 0, stream>>>(bsum, nScanBlocks);
    scan3_kernel<<<nScanBlocks, 256, 0, stream>>>(off, bsum, N);
    hipMemcpyAsync(cursor, off, (size_t)N * sizeof(int),
                   hipMemcpyDeviceToDevice, stream);
    fill_kernel<<<eGrid, 256, 0, stream>>>(ei, eattr, cursor, csr, E);
    // now: edges of node n are csr[off[n] .. cursor[n])

    const int gatherGrid = (N + 3) / 4;
    const int mlpGrid = (N + 63) / 64;

    // ---- layer 1 ----
    gather_kernel<<<gatherGrid, 256, 0, stream>>>(h, csr, off, cursor, ee_w, ee_b, z, N);
    mlp_kernel<<<mlpGrid, 256, 0, stream>>>(z, c1w1, c1b1, c1w2, c1b2, h, N);

    // ---- layer 2 ----
    gather_kernel<<<gatherGrid, 256, 0, stream>>>(h, csr, off, cursor, ee_w, ee_b, z, N);
    mlp_kernel<<<mlpGrid, 256, 0, stream>>>(z, c2w1, c2b1, c2w2, c2b2, h, N);

    // ---- mean pool ----
    hipMemsetAsync(sums, 0, (64 * H + 64) * sizeof(float), stream);
    pool_kernel<<<(N + 255) / 256, 64, 0, stream>>>(h, batch, sums, counts, N);
    div_kernel<<<64, 64, 0, stream>>>(sums, counts, (float*)d_out);
}